// Round 5
// baseline (79101.599 us; speedup 1.0000x reference)
//
#include <hip/hip_runtime.h>
#include <stdint.h>

#define DEV static __device__ __forceinline__

typedef float f32x4 __attribute__((ext_vector_type(4)));
typedef unsigned int u32x4 __attribute__((ext_vector_type(4)));
typedef _Float16 f16x8 __attribute__((ext_vector_type(8)));

DEV float sigm(float x) { return __fdividef(1.0f, 1.0f + __expf(-x)); }
DEV float tanh_(float x) { return 1.0f - __fdividef(2.0f, __expf(2.0f * x) + 1.0f); }

DEV f32x4 mfma16(f16x8 a, f16x8 b, f32x4 c) {
    return __builtin_amdgcn_mfma_f32_16x16x32_f16(a, b, c, 0, 0, 0);
}

// ---------------- packing pre-passes ----------------
__global__ __launch_bounds__(256) void cvt_f16(const float* __restrict__ src, _Float16* __restrict__ dst, int n) {
    int o = blockIdx.x * 256 + threadIdx.x;
    if (o < n) dst[o] = (_Float16)src[o];
}
// W_ih_l0 [1024][16] -> [1024][32] f16 zero-padded K
__global__ __launch_bounds__(256) void pad_wih0_f16(const float* __restrict__ src, _Float16* __restrict__ dst) {
    int o = blockIdx.x * 256 + threadIdx.x;   // 32768
    int k = o & 31, r = o >> 5;
    dst[o] = (k < 16) ? (_Float16)src[r * 16 + k] : (_Float16)0.f;
}
// x [B][T][16] f32 -> [B][T][32] f16 zero-padded K
__global__ __launch_bounds__(256) void pad_x_f16(const float* __restrict__ src, _Float16* __restrict__ dst) {
    int o = blockIdx.x * 256 + threadIdx.x;   // 8388608
    int k = o & 31;
    int t = (o >> 5) & 511;
    int b = o >> 14;
    dst[o] = (k < 16) ? (_Float16)src[((size_t)b * 512 + t) * 16 + k] : (_Float16)0.f;
}
// fc_w [64][512] -> [512][64]
__global__ __launch_bounds__(256) void transpose_fcw(const float* __restrict__ src, float* __restrict__ dst) {
    int o = blockIdx.x * 256 + threadIdx.x;   // 32768
    int j = o >> 6, l = o & 63;
    dst[o] = src[l * 512 + j];
}

// ---------------- island barrier (16 WGs share one batch strip) ----------------
DEV void island_barrier(int* cnt, int* flag, int members, int target) {
    __threadfence();                 // release: drain + make h writes device-visible
    __syncthreads();
    if (threadIdx.x == 0) {
        if (__hip_atomic_fetch_add(cnt, 1, __ATOMIC_ACQ_REL, __HIP_MEMORY_SCOPE_AGENT) == members - 1) {
            __hip_atomic_store(cnt, 0, __ATOMIC_RELAXED, __HIP_MEMORY_SCOPE_AGENT);
            __hip_atomic_store(flag, target, __ATOMIC_RELEASE, __HIP_MEMORY_SCOPE_AGENT);
        } else {
            while (__hip_atomic_load(flag, __ATOMIC_ACQUIRE, __HIP_MEMORY_SCOPE_AGENT) < target) {
                __builtin_amdgcn_s_sleep(2);
            }
        }
    }
    __syncthreads();
    __threadfence();                 // acquire: invalidate stale lines before reading new h
}

// ---------------- layer 0 persistent kernel ----------------
// grid = 2*nbt*16 WGs of 256. WG = (dir, bt strip of 64 rows, jblk of 16 j-cols).
// wave w owns i-tile w (16 rows) x 16 j x 4 gates. c in regs. W_hh slice persistent in LDS.
__global__ __launch_bounds__(256, 1) void l0_persist(
    int Bc, int nbt, int b0,
    const _Float16* __restrict__ xpad,
    const _Float16* __restrict__ WhhF, const _Float16* __restrict__ WhhB,  // [1024][256]
    const _Float16* __restrict__ WihF, const _Float16* __restrict__ WihB,  // [1024][32]
    const float* __restrict__ biasF, const float* __restrict__ biasB,
    _Float16* __restrict__ hbuf,       // [2 slot][2 dir][Bc][256]
    _Float16* __restrict__ out0,       // [512][Bc][512]
    int* __restrict__ sync)
{
    __shared__ _Float16 recW[16384];   // [64 rows][32 chunks swz][8]  32KB
    __shared__ _Float16 inpW[2048];    // [64 rows][4 chunks swz][8]    4KB

    int tid = threadIdx.x;
    int wave = tid >> 6, lane = tid & 63;
    int l15 = lane & 15, q = lane >> 4;
    int per_dir = nbt << 4;
    int wg = blockIdx.x;
    int dir = wg / per_dir;
    int rem = wg - dir * per_dir;
    int bt = rem >> 4;
    int jblk = rem & 15;
    int isl = dir * nbt + bt;
    int j0 = jblk * 16;
    int r_base = bt * 64 + wave * 16;

    const _Float16* Whh = dir ? WhhB : WhhF;
    const _Float16* Wih = dir ? WihB : WihF;
    const float* bias = dir ? biasB : biasF;

    // persistent W staging
    for (int it = 0; it < 8; ++it) {
        int idx = it * 256 + tid;          // 64 rows x 32 chunks
        int row = idx >> 5, c = idx & 31;
        *(u32x4*)(recW + (row * 32 + (c ^ (row & 7))) * 8) =
            *(const u32x4*)(Whh + (size_t)((row >> 4) * 256 + j0 + (row & 15)) * 256 + c * 8);
    }
    {
        int row = tid >> 2, c = tid & 3;   // 64 rows x 4 chunks
        *(u32x4*)(inpW + (row * 4 + (c ^ (row & 3))) * 8) =
            *(const u32x4*)(Wih + (size_t)((row >> 4) * 256 + j0 + (row & 15)) * 32 + c * 8);
    }
    __syncthreads();

    float bs[4];
    #pragma unroll
    for (int g = 0; g < 4; ++g) bs[g] = bias[g * 256 + j0 + l15];

    f32x4 creg = { 0.f, 0.f, 0.f, 0.f };
    const size_t slotStride = (size_t)2 * Bc * 256;

    #pragma unroll 1
    for (int s = 0; s < 512; ++s) {
        int t = dir ? (511 - s) : s;
        const _Float16* hRd = hbuf + (size_t)(s & 1) * slotStride + (size_t)dir * Bc * 256;
        _Float16* hWd = hbuf + (size_t)((s + 1) & 1) * slotStride + (size_t)dir * Bc * 256;

        f32x4 acc[4];
        #pragma unroll
        for (int g = 0; g < 4; ++g) { f32x4 v = { bs[g], bs[g], bs[g], bs[g] }; acc[g] = v; }

        // input term (K=32 padded)
        {
            f16x8 ax = *(const f16x8*)(xpad + ((size_t)(b0 + r_base + l15) * 512 + t) * 32 + q * 8);
            #pragma unroll
            for (int g = 0; g < 4; ++g)
                acc[g] = mfma16(ax, *(const f16x8*)(inpW + ((g * 16 + l15) * 4 + (q ^ (l15 & 3))) * 8), acc[g]);
        }
        // recurrent (K=256)
        #pragma unroll
        for (int k0 = 0; k0 < 256; k0 += 32) {
            f16x8 ah = *(const f16x8*)(hRd + (size_t)(r_base + l15) * 256 + k0 + q * 8);
            int cc = (k0 >> 3) + q;
            #pragma unroll
            for (int g = 0; g < 4; ++g)
                acc[g] = mfma16(ah, *(const f16x8*)(recW + ((g * 16 + l15) * 32 + (cc ^ (l15 & 7))) * 8), acc[g]);
        }
        // epilogue
        #pragma unroll
        for (int e = 0; e < 4; ++e) {
            int r = r_base + q * 4 + e;
            float cn = sigm(acc[1][e]) * creg[e] + sigm(acc[0][e]) * tanh_(acc[2][e]);
            creg[e] = cn;
            float h = sigm(acc[3][e]) * tanh_(cn);
            _Float16 h16 = (_Float16)h;
            hWd[(size_t)r * 256 + j0 + l15] = h16;
            out0[((size_t)t * Bc + r) * 512 + dir * 256 + j0 + l15] = h16;
        }
        if (s < 511) island_barrier(&sync[isl * 2], &sync[isl * 2 + 1], 16, s + 1);
    }
}

// ---------------- layer 1 persistent kernel ----------------
// in-step input GEMM: out0_t @ W_ih1^T, W1 staged in LDS quarters (K=128 each).
__global__ __launch_bounds__(256, 1) void l1_persist(
    int Bc, int nbt,
    const _Float16* __restrict__ out0,                                     // [512][Bc][512]
    const _Float16* __restrict__ WhhF, const _Float16* __restrict__ WhhB,  // [1024][256]
    const _Float16* __restrict__ WihF, const _Float16* __restrict__ WihB,  // [1024][512]
    const float* __restrict__ biasF, const float* __restrict__ biasB,
    _Float16* __restrict__ hbuf, int* __restrict__ sync)
{
    __shared__ _Float16 recW[16384];   // 32KB persistent
    __shared__ _Float16 inpB[8192];    // [64 rows][16 chunks swz][8] 16KB staged per quarter

    int tid = threadIdx.x;
    int wave = tid >> 6, lane = tid & 63;
    int l15 = lane & 15, q = lane >> 4;
    int per_dir = nbt << 4;
    int wg = blockIdx.x;
    int dir = wg / per_dir;
    int rem = wg - dir * per_dir;
    int bt = rem >> 4;
    int jblk = rem & 15;
    int isl = dir * nbt + bt;
    int j0 = jblk * 16;
    int r_base = bt * 64 + wave * 16;

    const _Float16* Whh = dir ? WhhB : WhhF;
    const _Float16* W1  = dir ? WihB : WihF;
    const float* bias = dir ? biasB : biasF;

    for (int it = 0; it < 8; ++it) {
        int idx = it * 256 + tid;
        int row = idx >> 5, c = idx & 31;
        *(u32x4*)(recW + (row * 32 + (c ^ (row & 7))) * 8) =
            *(const u32x4*)(Whh + (size_t)((row >> 4) * 256 + j0 + (row & 15)) * 256 + c * 8);
    }
    __syncthreads();

    float bs[4];
    #pragma unroll
    for (int g = 0; g < 4; ++g) bs[g] = bias[g * 256 + j0 + l15];

    f32x4 creg = { 0.f, 0.f, 0.f, 0.f };
    const size_t slotStride = (size_t)2 * Bc * 256;

    #pragma unroll 1
    for (int s = 0; s < 512; ++s) {
        int t = dir ? (511 - s) : s;
        const _Float16* hRd = hbuf + (size_t)(s & 1) * slotStride + (size_t)dir * Bc * 256;
        _Float16* hWd = hbuf + (size_t)((s + 1) & 1) * slotStride + (size_t)dir * Bc * 256;

        f32x4 acc[4];
        #pragma unroll
        for (int g = 0; g < 4; ++g) { f32x4 v = { bs[g], bs[g], bs[g], bs[g] }; acc[g] = v; }

        // recurrent (K=256) from persistent LDS
        #pragma unroll
        for (int k0 = 0; k0 < 256; k0 += 32) {
            f16x8 ah = *(const f16x8*)(hRd + (size_t)(r_base + l15) * 256 + k0 + q * 8);
            int cc = (k0 >> 3) + q;
            #pragma unroll
            for (int g = 0; g < 4; ++g)
                acc[g] = mfma16(ah, *(const f16x8*)(recW + ((g * 16 + l15) * 32 + (cc ^ (l15 & 7))) * 8), acc[g]);
        }
        // input GEMM (K=512) in 4 staged quarters of 128
        #pragma unroll 1
        for (int kq = 0; kq < 4; ++kq) {
            __syncthreads();   // prior readers of inpB done
            #pragma unroll
            for (int it = 0; it < 4; ++it) {
                int idx = it * 256 + tid;      // 64 rows x 16 chunks
                int row = idx >> 4, c = idx & 15;
                *(u32x4*)(inpB + (row * 16 + (c ^ (row & 7))) * 8) =
                    *(const u32x4*)(W1 + (size_t)((row >> 4) * 256 + j0 + (row & 15)) * 512 + kq * 128 + c * 8);
            }
            __syncthreads();
            #pragma unroll
            for (int k0 = 0; k0 < 128; k0 += 32) {
                f16x8 aa = *(const f16x8*)(out0 + ((size_t)t * Bc + r_base + l15) * 512 + kq * 128 + k0 + q * 8);
                int cc = (k0 >> 3) + q;
                #pragma unroll
                for (int g = 0; g < 4; ++g)
                    acc[g] = mfma16(aa, *(const f16x8*)(inpB + ((g * 16 + l15) * 16 + (cc ^ (l15 & 7))) * 8), acc[g]);
            }
        }
        // epilogue
        #pragma unroll
        for (int e = 0; e < 4; ++e) {
            int r = r_base + q * 4 + e;
            float cn = sigm(acc[1][e]) * creg[e] + sigm(acc[0][e]) * tanh_(acc[2][e]);
            creg[e] = cn;
            float h = sigm(acc[3][e]) * tanh_(cn);
            hWd[(size_t)r * 256 + j0 + l15] = (_Float16)h;
        }
        if (s < 511) island_barrier(&sync[isl * 2], &sync[isl * 2 + 1], 16, s + 1);
    }
}

// ---------------- final FC ----------------
__global__ __launch_bounds__(64) void fc_kernel(
    const _Float16* __restrict__ h /* slot0: [2 dir][Bc][256] */,
    const float* __restrict__ fcwT, const float* __restrict__ fcb,
    float* __restrict__ out, int b0, int Bc)
{
    __shared__ float hc[512];
    int b = blockIdx.x, l = threadIdx.x;
    #pragma unroll
    for (int it = 0; it < 8; ++it) {
        int jj = it * 64 + l;
        int d = jj >> 8, j = jj & 255;
        hc[jj] = (float)h[((size_t)d * Bc + b) * 256 + j];
    }
    __syncthreads();
    float acc = fcb[l];
    for (int j = 0; j < 512; ++j) acc += hc[j] * fcwT[j * 64 + l];
    out[(b0 + b) * 64 + l] = acc;
}

// ---------------- host ----------------
extern "C" void kernel_launch(void* const* d_in, const int* in_sizes, int n_in,
                              void* d_out, int out_size, void* d_ws, size_t ws_size,
                              hipStream_t stream)
{
    const float* x     = (const float*)d_in[0];
    const float* wih0f = (const float*)d_in[1];
    const float* whh0f = (const float*)d_in[2];
    const float* b0f   = (const float*)d_in[3];
    const float* wih0b = (const float*)d_in[4];
    const float* whh0b = (const float*)d_in[5];
    const float* b0b   = (const float*)d_in[6];
    const float* wih1f = (const float*)d_in[7];
    const float* whh1f = (const float*)d_in[8];
    const float* b1f   = (const float*)d_in[9];
    const float* wih1b = (const float*)d_in[10];
    const float* whh1b = (const float*)d_in[11];
    const float* b1b   = (const float*)d_in[12];
    const float* fcw   = (const float*)d_in[13];
    const float* fcb   = (const float*)d_in[14];
    float* out = (float*)d_out;
    (void)in_sizes; (void)n_in; (void)out_size;

    // per-row bytes: out0 512*512*2 + hbuf 2*2*256*2
    const size_t per_row = 524288 + 2048;
    const size_t fixed   = 24u * 1048576;
    int Bc = 512;
    while (Bc > 64 && fixed + per_row * (size_t)Bc > ws_size) Bc >>= 1;
    const int nb = 512 / Bc;
    const int nbt = Bc / 64;
    const int grid = 32 * nbt;      // 2 dirs * nbt strips * 16 jblk

    char* p = (char*)d_ws;
    auto alloc = [&](size_t bytes) -> void* {
        void* r = (void*)p;
        p += (bytes + 255) & ~(size_t)255;
        return r;
    };
    _Float16* Whh0f16 = (_Float16*)alloc(262144 * 2);
    _Float16* Whh0b16 = (_Float16*)alloc(262144 * 2);
    _Float16* Whh1f16 = (_Float16*)alloc(262144 * 2);
    _Float16* Whh1b16 = (_Float16*)alloc(262144 * 2);
    _Float16* Wih0pf  = (_Float16*)alloc(32768 * 2);
    _Float16* Wih0pb  = (_Float16*)alloc(32768 * 2);
    _Float16* Wih1f16 = (_Float16*)alloc(524288 * 2);
    _Float16* Wih1b16 = (_Float16*)alloc(524288 * 2);
    _Float16* xpad    = (_Float16*)alloc((size_t)512 * 512 * 32 * 2);
    float*    fcwT    = (float*)alloc(512 * 64 * 4);
    int*      syncA   = (int*)alloc(4096);
    _Float16* hbuf    = (_Float16*)alloc((size_t)2 * 2 * Bc * 256 * 2);
    _Float16* out0    = (_Float16*)alloc((size_t)512 * Bc * 512 * 2);

    cvt_f16<<<1024, 256, 0, stream>>>(whh0f, Whh0f16, 262144);
    cvt_f16<<<1024, 256, 0, stream>>>(whh0b, Whh0b16, 262144);
    cvt_f16<<<1024, 256, 0, stream>>>(whh1f, Whh1f16, 262144);
    cvt_f16<<<1024, 256, 0, stream>>>(whh1b, Whh1b16, 262144);
    cvt_f16<<<2048, 256, 0, stream>>>(wih1f, Wih1f16, 524288);
    cvt_f16<<<2048, 256, 0, stream>>>(wih1b, Wih1b16, 524288);
    pad_wih0_f16<<<128, 256, 0, stream>>>(wih0f, Wih0pf);
    pad_wih0_f16<<<128, 256, 0, stream>>>(wih0b, Wih0pb);
    pad_x_f16<<<32768, 256, 0, stream>>>(x, xpad);
    transpose_fcw<<<128, 256, 0, stream>>>(fcw, fcwT);

    const size_t hbytes = (size_t)2 * 2 * Bc * 256 * 2;

    for (int bchunk = 0; bchunk < nb; ++bchunk) {
        int b0 = bchunk * Bc;

        hipMemsetAsync(hbuf, 0, hbytes, stream);
        hipMemsetAsync(syncA, 0, 4096, stream);
        l0_persist<<<grid, 256, 0, stream>>>(Bc, nbt, b0, xpad,
            Whh0f16, Whh0b16, Wih0pf, Wih0pb, b0f, b0b, hbuf, out0, syncA);

        hipMemsetAsync(hbuf, 0, hbytes, stream);
        hipMemsetAsync(syncA, 0, 4096, stream);
        l1_persist<<<grid, 256, 0, stream>>>(Bc, nbt, out0,
            Whh1f16, Whh1b16, Wih1f16, Wih1b16, b1f, b1b, hbuf, syncA);

        fc_kernel<<<Bc, 64, 0, stream>>>(hbuf, fcwT, fcb, out, b0, Bc);
    }
}

// Round 7
// 21855.203 us; speedup vs baseline: 3.6193x; 3.6193x over previous
//
#include <hip/hip_runtime.h>
#include <stdint.h>

#define DEV static __device__ __forceinline__

typedef float f32x4 __attribute__((ext_vector_type(4)));
typedef unsigned int u32x4 __attribute__((ext_vector_type(4)));
typedef _Float16 f16x8 __attribute__((ext_vector_type(8)));

DEV float sigm(float x) { return __fdividef(1.0f, 1.0f + __expf(-x)); }
DEV float tanh_(float x) { return 1.0f - __fdividef(2.0f, __expf(2.0f * x) + 1.0f); }

DEV f32x4 mfma16(f16x8 a, f16x8 b, f32x4 c) {
    return __builtin_amdgcn_mfma_f32_16x16x32_f16(a, b, c, 0, 0, 0);
}

// ---------------- packing pre-passes ----------------
__global__ __launch_bounds__(256) void cvt_f16(const float* __restrict__ src, _Float16* __restrict__ dst, int n) {
    int o = blockIdx.x * 256 + threadIdx.x;
    if (o < n) dst[o] = (_Float16)src[o];
}
// W_ih_l0 [1024][16] -> [1024][32] f16 zero-padded K
__global__ __launch_bounds__(256) void pad_wih0_f16(const float* __restrict__ src, _Float16* __restrict__ dst) {
    int o = blockIdx.x * 256 + threadIdx.x;   // 32768
    int k = o & 31, r = o >> 5;
    dst[o] = (k < 16) ? (_Float16)src[r * 16 + k] : (_Float16)0.f;
}
// x [B][T][16] f32 -> [B][T][32] f16 zero-padded K
__global__ __launch_bounds__(256) void pad_x_f16(const float* __restrict__ src, _Float16* __restrict__ dst) {
    int o = blockIdx.x * 256 + threadIdx.x;   // 8388608
    int k = o & 31;
    int t = (o >> 5) & 511;
    int b = o >> 14;
    dst[o] = (k < 16) ? (_Float16)src[((size_t)b * 512 + t) * 16 + k] : (_Float16)0.f;
}
// fc_w [64][512] -> [512][64]
__global__ __launch_bounds__(256) void transpose_fcw(const float* __restrict__ src, float* __restrict__ dst) {
    int o = blockIdx.x * 256 + threadIdx.x;   // 32768
    int j = o >> 6, l = o & 63;
    dst[o] = src[l * 512 + j];
}

// ---------------- cross-WG step sync: fresh flag slot per (island, step) ----------------
// No fences: h data moves via agent-scope (LLC) relaxed atomics; release = vmcnt(0) drain.
DEV void island_sync(int* flagp, int members) {
    asm volatile("s_waitcnt vmcnt(0)" ::: "memory");   // h atomic stores now at LLC
    __syncthreads();
    if (threadIdx.x == 0) {
        __hip_atomic_fetch_add(flagp, 1, __ATOMIC_RELAXED, __HIP_MEMORY_SCOPE_AGENT);
        while (__hip_atomic_load(flagp, __ATOMIC_RELAXED, __HIP_MEMORY_SCOPE_AGENT) < members)
            __builtin_amdgcn_s_sleep(1);
    }
    __syncthreads();
    asm volatile("" ::: "memory");                     // no load hoisting above the sync
}

// load A-fragment (8 f16) from f32 h state via agent-coherent (LLC) atomic loads
DEV f16x8 load_h_frag(const float* hp) {
    unsigned long long d[4];
    #pragma unroll
    for (int i = 0; i < 4; ++i)
        d[i] = __hip_atomic_load((const unsigned long long*)hp + i,
                                 __ATOMIC_RELAXED, __HIP_MEMORY_SCOPE_AGENT);
    f16x8 v;
    #pragma unroll
    for (int i = 0; i < 4; ++i) {
        union { unsigned long long u; float f[2]; } c; c.u = d[i];
        v[2 * i]     = (_Float16)c.f[0];
        v[2 * i + 1] = (_Float16)c.f[1];
    }
    return v;
}

// LDS W slice: 16B segment index for (jj in [0,16), gate, c5 = k0*4+q), XOR-swizzled
DEV int wseg(int jj, int g, int c5) { return jj * 128 + g * 32 + (c5 ^ (jj & 7)); }

// ---------------- layer 0 persistent ----------------
// grid = 32*nbt WGs of 256 thr. bid = isl*16 + jblk; isl = dir*nbt + strip.
// WG owns 64 batch rows (strip) x 16 j-cols; wave = i-tile (16 rows). c in regs.
// W_hh slice (32KB) persistent in LDS. h: f32 [2 slot][2 dir][Bc][256] via LLC atomics.
__global__ __launch_bounds__(256) void l0_persist(
    int Bc, int b0, int nbt_bits,
    const _Float16* __restrict__ xpad,
    const _Float16* __restrict__ WhhF, const _Float16* __restrict__ WhhB,
    const _Float16* __restrict__ WihF, const _Float16* __restrict__ WihB,
    const float* __restrict__ bF, const float* __restrict__ bB,
    float* __restrict__ hbuf, _Float16* __restrict__ out0, int* __restrict__ flags)
{
    __shared__ _Float16 recW[16384];   // 32KB
    int tid = threadIdx.x;
    int wave = tid >> 6, lane = tid & 63, l15 = lane & 15, q = lane >> 4;
    int jblk = blockIdx.x & 15;
    int isl = blockIdx.x >> 4;
    int nbt = 1 << nbt_bits;
    int strip = isl & (nbt - 1), dir = isl >> nbt_bits;
    int j0 = jblk * 16;
    int r0w = strip * 64 + wave * 16;

    const _Float16* Whh = dir ? WhhB : WhhF;
    const _Float16* Wih = dir ? WihB : WihF;
    const float* bias = dir ? bB : bF;

    #pragma unroll
    for (int it = 0; it < 8; ++it) {
        int idx = it * 256 + tid;          // 2048 16B segments
        int jj = idx >> 7, r = idx & 127;
        int g = r >> 5, c5 = r & 31;
        *(u32x4*)(recW + wseg(jj, g, c5) * 8) =
            *(const u32x4*)(Whh + (size_t)(g * 256 + jblk * 16 + jj) * 256 + c5 * 8);
    }
    __syncthreads();

    float bs[4];
    f16x8 bx[4];
    #pragma unroll
    for (int g = 0; g < 4; ++g) {
        bs[g] = bias[g * 256 + j0 + l15];
        bx[g] = *(const f16x8*)(Wih + (size_t)(g * 256 + j0 + l15) * 32 + q * 8);
    }

    f32x4 creg = { 0.f, 0.f, 0.f, 0.f };
    const size_t slotStride = (size_t)2 * Bc * 256;

    #pragma unroll 1
    for (int s = 0; s < 512; ++s) {
        int t = dir ? (511 - s) : s;
        const float* hR = hbuf + (size_t)(s & 1) * slotStride + (size_t)dir * (Bc * 256);
        float* hW = hbuf + (size_t)((s + 1) & 1) * slotStride + (size_t)dir * (Bc * 256);

        f32x4 acc[4];
        #pragma unroll
        for (int g = 0; g < 4; ++g) { f32x4 v = { bs[g], bs[g], bs[g], bs[g] }; acc[g] = v; }

        // input term (K=32, weights in regs)
        {
            f16x8 ax = *(const f16x8*)(xpad + ((size_t)(b0 + r0w + l15) * 512 + t) * 32 + q * 8);
            #pragma unroll
            for (int g = 0; g < 4; ++g) acc[g] = mfma16(ax, bx[g], acc[g]);
        }
        // recurrent (K=256): A from LLC h, B from persistent LDS
        #pragma unroll
        for (int k0 = 0; k0 < 8; ++k0) {
            f16x8 ah = load_h_frag(hR + (size_t)(r0w + l15) * 256 + k0 * 32 + q * 8);
            int c5 = k0 * 4 + q;
            #pragma unroll
            for (int g = 0; g < 4; ++g)
                acc[g] = mfma16(ah, *(const f16x8*)(recW + wseg(l15, g, c5) * 8), acc[g]);
        }
        // epilogue
        #pragma unroll
        for (int e = 0; e < 4; ++e) {
            int r = r0w + q * 4 + e;
            float cn = sigm(acc[1][e]) * creg[e] + sigm(acc[0][e]) * tanh_(acc[2][e]);
            creg[e] = cn;
            float h = sigm(acc[3][e]) * tanh_(cn);
            union { float f; unsigned u; } hb; hb.f = h;
            __hip_atomic_store((unsigned*)(hW + (size_t)r * 256 + j0 + l15), hb.u,
                               __ATOMIC_RELAXED, __HIP_MEMORY_SCOPE_AGENT);
            out0[((size_t)t * Bc + r) * 512 + dir * 256 + j0 + l15] = (_Float16)h;
        }
        if (s < 511) island_sync(flags + isl * 512 + s, 16);
    }
}

// ---------------- layer 1 persistent ----------------
// adds in-step input GEMM: out0_t @ W1^T, B-frags streamed from L2.
__global__ __launch_bounds__(256) void l1_persist(
    int Bc, int nbt_bits,
    const _Float16* __restrict__ out0,
    const _Float16* __restrict__ WhhF, const _Float16* __restrict__ WhhB,
    const _Float16* __restrict__ W1F, const _Float16* __restrict__ W1B,
    const float* __restrict__ bF, const float* __restrict__ bB,
    float* __restrict__ hbuf, int* __restrict__ flags)
{
    __shared__ _Float16 recW[16384];
    int tid = threadIdx.x;
    int wave = tid >> 6, lane = tid & 63, l15 = lane & 15, q = lane >> 4;
    int jblk = blockIdx.x & 15;
    int isl = blockIdx.x >> 4;
    int nbt = 1 << nbt_bits;
    int strip = isl & (nbt - 1), dir = isl >> nbt_bits;
    int j0 = jblk * 16;
    int r0w = strip * 64 + wave * 16;

    const _Float16* Whh = dir ? WhhB : WhhF;
    const _Float16* W1 = dir ? W1B : W1F;
    const float* bias = dir ? bB : bF;

    #pragma unroll
    for (int it = 0; it < 8; ++it) {
        int idx = it * 256 + tid;
        int jj = idx >> 7, r = idx & 127;
        int g = r >> 5, c5 = r & 31;
        *(u32x4*)(recW + wseg(jj, g, c5) * 8) =
            *(const u32x4*)(Whh + (size_t)(g * 256 + jblk * 16 + jj) * 256 + c5 * 8);
    }
    __syncthreads();

    float bs[4];
    #pragma unroll
    for (int g = 0; g < 4; ++g) bs[g] = bias[g * 256 + j0 + l15];

    f32x4 creg = { 0.f, 0.f, 0.f, 0.f };
    const size_t slotStride = (size_t)2 * Bc * 256;

    #pragma unroll 1
    for (int s = 0; s < 512; ++s) {
        int t = dir ? (511 - s) : s;
        const float* hR = hbuf + (size_t)(s & 1) * slotStride + (size_t)dir * (Bc * 256);
        float* hW = hbuf + (size_t)((s + 1) & 1) * slotStride + (size_t)dir * (Bc * 256);

        f32x4 acc[4];
        #pragma unroll
        for (int g = 0; g < 4; ++g) { f32x4 v = { bs[g], bs[g], bs[g], bs[g] }; acc[g] = v; }

        // input GEMM (K=512): A = out0[t] rows, B streamed (L1/L2-resident)
        #pragma unroll 2
        for (int k0 = 0; k0 < 16; ++k0) {
            f16x8 aa = *(const f16x8*)(out0 + ((size_t)t * Bc + r0w + l15) * 512 + k0 * 32 + q * 8);
            #pragma unroll
            for (int g = 0; g < 4; ++g) {
                f16x8 bb = *(const f16x8*)(W1 + (size_t)(g * 256 + j0 + l15) * 512 + k0 * 32 + q * 8);
                acc[g] = mfma16(aa, bb, acc[g]);
            }
        }
        // recurrent (K=256)
        #pragma unroll
        for (int k0 = 0; k0 < 8; ++k0) {
            f16x8 ah = load_h_frag(hR + (size_t)(r0w + l15) * 256 + k0 * 32 + q * 8);
            int c5 = k0 * 4 + q;
            #pragma unroll
            for (int g = 0; g < 4; ++g)
                acc[g] = mfma16(ah, *(const f16x8*)(recW + wseg(l15, g, c5) * 8), acc[g]);
        }
        // epilogue
        #pragma unroll
        for (int e = 0; e < 4; ++e) {
            int r = r0w + q * 4 + e;
            float cn = sigm(acc[1][e]) * creg[e] + sigm(acc[0][e]) * tanh_(acc[2][e]);
            creg[e] = cn;
            float h = sigm(acc[3][e]) * tanh_(cn);
            union { float f; unsigned u; } hb; hb.f = h;
            __hip_atomic_store((unsigned*)(hW + (size_t)r * 256 + j0 + l15), hb.u,
                               __ATOMIC_RELAXED, __HIP_MEMORY_SCOPE_AGENT);
        }
        if (s < 511) island_sync(flags + isl * 512 + s, 16);
    }
}

// ---------------- final FC ----------------
__global__ __launch_bounds__(64) void fc_kernel(
    const float* __restrict__ h /* slot0: [2 dir][Bc][256] f32 */,
    const float* __restrict__ fcwT, const float* __restrict__ fcb,
    float* __restrict__ out, int b0, int Bc)
{
    __shared__ float hc[512];
    int b = blockIdx.x, l = threadIdx.x;
    #pragma unroll
    for (int it = 0; it < 8; ++it) {
        int jj = it * 64 + l;
        int d = jj >> 8, j = jj & 255;
        hc[jj] = h[((size_t)d * Bc + b) * 256 + j];
    }
    __syncthreads();
    float acc = fcb[l];
    for (int j = 0; j < 512; ++j) acc += hc[j] * fcwT[j * 64 + l];
    out[(b0 + b) * 64 + l] = acc;
}

// ---------------- host ----------------
extern "C" void kernel_launch(void* const* d_in, const int* in_sizes, int n_in,
                              void* d_out, int out_size, void* d_ws, size_t ws_size,
                              hipStream_t stream)
{
    const float* x     = (const float*)d_in[0];
    const float* wih0f = (const float*)d_in[1];
    const float* whh0f = (const float*)d_in[2];
    const float* b0f   = (const float*)d_in[3];
    const float* wih0b = (const float*)d_in[4];
    const float* whh0b = (const float*)d_in[5];
    const float* b0b   = (const float*)d_in[6];
    const float* wih1f = (const float*)d_in[7];
    const float* whh1f = (const float*)d_in[8];
    const float* b1f   = (const float*)d_in[9];
    const float* wih1b = (const float*)d_in[10];
    const float* whh1b = (const float*)d_in[11];
    const float* b1b   = (const float*)d_in[12];
    const float* fcw   = (const float*)d_in[13];
    const float* fcb   = (const float*)d_in[14];
    float* out = (float*)d_out;
    (void)in_sizes; (void)n_in; (void)out_size;

    // adaptive batch chunk: per_row = out0 (512*512*2) + hbuf (2*2*256*4)
    const size_t per_row = 524288 + 8192;
    const size_t fixed   = 24u * 1048576;   // xpad 16MB + weights ~4.3MB + misc, rounded up
    int Bc = 512;
    while (Bc > 64 && fixed + per_row * (size_t)Bc > ws_size) Bc >>= 1;
    const int nb = 512 / Bc;
    const int nbt = Bc / 64;
    const int nbt_bits = 31 - __builtin_clz((unsigned)nbt);
    const int grid = 32 * nbt;              // (2*nbt islands) x 16 jblk

    char* p = (char*)d_ws;
    auto alloc = [&](size_t bytes) -> void* {
        void* r = (void*)p;
        p += (bytes + 255) & ~(size_t)255;
        return r;
    };
    _Float16* Whh0f16 = (_Float16*)alloc(262144 * 2);
    _Float16* Whh0b16 = (_Float16*)alloc(262144 * 2);
    _Float16* Whh1f16 = (_Float16*)alloc(262144 * 2);
    _Float16* Whh1b16 = (_Float16*)alloc(262144 * 2);
    _Float16* Wih0pf  = (_Float16*)alloc(32768 * 2);
    _Float16* Wih0pb  = (_Float16*)alloc(32768 * 2);
    _Float16* Wih1f16 = (_Float16*)alloc(524288 * 2);
    _Float16* Wih1b16 = (_Float16*)alloc(524288 * 2);
    _Float16* xpad    = (_Float16*)alloc((size_t)512 * 512 * 32 * 2);
    float*    fcwT    = (float*)alloc(512 * 64 * 4);
    int*      flags   = (int*)alloc(2 * 16 * 512 * 4);                // [layer][isl<=16][step]
    float*    hbuf    = (float*)alloc((size_t)2 * 2 * Bc * 256 * 4);  // [slot][dir][b][k] f32
    _Float16* out0    = (_Float16*)alloc((size_t)512 * Bc * 512 * 2); // [t][b][2H] f16

    cvt_f16<<<1024, 256, 0, stream>>>(whh0f, Whh0f16, 262144);
    cvt_f16<<<1024, 256, 0, stream>>>(whh0b, Whh0b16, 262144);
    cvt_f16<<<1024, 256, 0, stream>>>(whh1f, Whh1f16, 262144);
    cvt_f16<<<1024, 256, 0, stream>>>(whh1b, Whh1b16, 262144);
    cvt_f16<<<2048, 256, 0, stream>>>(wih1f, Wih1f16, 524288);
    cvt_f16<<<2048, 256, 0, stream>>>(wih1b, Wih1b16, 524288);
    pad_wih0_f16<<<128, 256, 0, stream>>>(wih0f, Wih0pf);
    pad_wih0_f16<<<128, 256, 0, stream>>>(wih0b, Wih0pb);
    pad_x_f16<<<32768, 256, 0, stream>>>(x, xpad);
    transpose_fcw<<<128, 256, 0, stream>>>(fcw, fcwT);

    const size_t hbytes = (size_t)2 * 2 * Bc * 256 * 4;

    for (int bchunk = 0; bchunk < nb; ++bchunk) {
        int b0 = bchunk * Bc;

        hipMemsetAsync(flags, 0, 2 * 16 * 512 * 4, stream);
        hipMemsetAsync(hbuf, 0, hbytes, stream);
        l0_persist<<<grid, 256, 0, stream>>>(Bc, b0, nbt_bits, xpad,
            Whh0f16, Whh0b16, Wih0pf, Wih0pb, b0f, b0b, hbuf, out0, flags);

        hipMemsetAsync(hbuf, 0, hbytes, stream);
        l1_persist<<<grid, 256, 0, stream>>>(Bc, nbt_bits, out0,
            Whh1f16, Whh1b16, Wih1f16, Wih1b16, b1f, b1b, hbuf, flags + 16 * 512);

        fc_kernel<<<Bc, 64, 0, stream>>>(hbuf, fcwT, fcb, out, b0, Bc);
    }
}

// Round 8
// 9215.993 us; speedup vs baseline: 8.5831x; 2.3714x over previous
//
#include <hip/hip_runtime.h>
#include <stdint.h>

#define DEV static __device__ __forceinline__

typedef float f32x4 __attribute__((ext_vector_type(4)));
typedef unsigned int u32x4 __attribute__((ext_vector_type(4)));
typedef _Float16 f16x8 __attribute__((ext_vector_type(8)));
typedef unsigned long long u64;

DEV float sigm(float x) { return __fdividef(1.0f, 1.0f + __expf(-x)); }
DEV float tanh_(float x) { return 1.0f - __fdividef(2.0f, __expf(2.0f * x) + 1.0f); }

DEV f32x4 mfma16(f16x8 a, f16x8 b, f32x4 c) {
    return __builtin_amdgcn_mfma_f32_16x16x32_f16(a, b, c, 0, 0, 0);
}

// relaxed agent-scope (LLC-coherent) ops — mechanism validated by R7
DEV int aload_i(const int* p) { return __hip_atomic_load(p, __ATOMIC_RELAXED, __HIP_MEMORY_SCOPE_AGENT); }
DEV void astore_i(int* p, int v) { __hip_atomic_store(p, v, __ATOMIC_RELAXED, __HIP_MEMORY_SCOPE_AGENT); }
DEV u64 aload_u64(const void* p) { return __hip_atomic_load((const u64*)p, __ATOMIC_RELAXED, __HIP_MEMORY_SCOPE_AGENT); }
DEV void astore_u64(void* p, u64 v) { __hip_atomic_store((u64*)p, v, __ATOMIC_RELAXED, __HIP_MEMORY_SCOPE_AGENT); }

DEV f16x8 mk_f16x8(u64 a, u64 b) { union { u64 u[2]; f16x8 v; } c; c.u[0] = a; c.u[1] = b; return c.v; }
DEV f32x4 mk_f32x4(u64 a, u64 b) { union { u64 u[2]; f32x4 v; } c; c.u[0] = a; c.u[1] = b; return c.v; }
DEV void un_f32x4(f32x4 x, u64* a, u64* b) { union { f32x4 v; u64 u[2]; } c; c.v = x; *a = c.u[0]; *b = c.u[1]; }

// ---------------- packing pre-passes ----------------
__global__ __launch_bounds__(256) void cvt_f16(const float* __restrict__ src, _Float16* __restrict__ dst, int n) {
    int o = blockIdx.x * 256 + threadIdx.x;
    if (o < n) dst[o] = (_Float16)src[o];
}
__global__ __launch_bounds__(256) void pad_wih0_f16(const float* __restrict__ src, _Float16* __restrict__ dst) {
    int o = blockIdx.x * 256 + threadIdx.x;   // 32768
    int k = o & 31, r = o >> 5;
    dst[o] = (k < 16) ? (_Float16)src[r * 16 + k] : (_Float16)0.f;
}
__global__ __launch_bounds__(256) void pad_x_f16(const float* __restrict__ src, _Float16* __restrict__ dst) {
    int o = blockIdx.x * 256 + threadIdx.x;   // 8388608
    int k = o & 31;
    int t = (o >> 5) & 511;
    int b = o >> 14;
    dst[o] = (k < 16) ? (_Float16)src[((size_t)b * 512 + t) * 16 + k] : (_Float16)0.f;
}
__global__ __launch_bounds__(256) void transpose_fcw(const float* __restrict__ src, float* __restrict__ dst) {
    int o = blockIdx.x * 256 + threadIdx.x;   // 32768
    int j = o >> 6, l = o & 63;
    dst[o] = src[l * 512 + j];
}

// LDS W slice: 16B segment index for (jj in [0,16), gate, c5 = k0*4+q), XOR swizzle (R7-validated)
DEV int wseg(int jj, int g, int c5) { return jj * 128 + g * 32 + (c5 ^ (jj & 7)); }

// ---------------- layer 0 persistent (dataflow-sync) ----------------
// grid = 32*S WGs of 256. bid = isl*16 + jblk; isl = dir*S + strip (strip of 64 batch rows).
// h ring: [4 slot][2 dir][S][16 jblkW][64 r][16 j] f16, LLC atomics. seq[slot][isl][jblk] pad 64B.
__global__ __launch_bounds__(256) void l0_persist(
    int S, int sbits, int Bc, int b0,
    const _Float16* __restrict__ xpad,
    const _Float16* __restrict__ WhhF, const _Float16* __restrict__ WhhB,
    const _Float16* __restrict__ WihF, const _Float16* __restrict__ WihB,
    const float* __restrict__ bF, const float* __restrict__ bB,
    _Float16* __restrict__ hring, int* __restrict__ seq, _Float16* __restrict__ out0)
{
    __shared__ _Float16 recW[16384];   // 32KB
    __shared__ _Float16 hstage[1024];  // 2KB
    int tid = threadIdx.x;
    int wave = tid >> 6, lane = tid & 63, l15 = lane & 15, q = lane >> 4;
    int jblk = blockIdx.x & 15;
    int isl = blockIdx.x >> 4;
    int NI = 2 * S;
    int dir = isl >> sbits, strip = isl & (S - 1);

    const _Float16* Whh = dir ? WhhB : WhhF;
    const _Float16* Wih = dir ? WihB : WihF;
    const float* bias = dir ? bB : bF;

    #pragma unroll
    for (int it = 0; it < 8; ++it) {
        int idx = it * 256 + tid;
        int jj = idx >> 7, r = idx & 127;
        int g = r >> 5, c5 = r & 31;
        *(u32x4*)(recW + wseg(jj, g, c5) * 8) =
            *(const u32x4*)(Whh + (size_t)(g * 256 + jblk * 16 + jj) * 256 + c5 * 8);
    }
    __syncthreads();

    float bs[4]; f16x8 bx[4];
    #pragma unroll
    for (int g = 0; g < 4; ++g) {
        bs[g] = bias[g * 256 + jblk * 16 + l15];
        bx[g] = *(const f16x8*)(Wih + (size_t)(g * 256 + jblk * 16 + l15) * 32 + q * 8);
    }

    f32x4 creg = { 0.f, 0.f, 0.f, 0.f };

    #pragma unroll 1
    for (int s = 0; s < 512; ++s) {
        int t = dir ? (511 - s) : s;
        {   // wait for partners' h[s] at slot s&3 (value s)
            int* sp = seq + ((size_t)((s & 3) * NI + isl) * 16 + (lane & 15)) * 16;
            for (;;) {
                int ok = 1;
                if (lane < 16) ok = (aload_i(sp) >= s);
                if (__all(ok)) break;
                __builtin_amdgcn_s_sleep(1);
            }
        }
        asm volatile("" ::: "memory");

        f32x4 acc[4];
        #pragma unroll
        for (int g = 0; g < 4; ++g) { f32x4 v = { bs[g], bs[g], bs[g], bs[g] }; acc[g] = v; }

        {   // input term K=32
            f16x8 ax = *(const f16x8*)(xpad + ((size_t)(b0 + strip * 64 + wave * 16 + l15) * 512 + t) * 32 + q * 8);
            #pragma unroll
            for (int g = 0; g < 4; ++g) acc[g] = mfma16(ax, bx[g], acc[g]);
        }
        // recurrent K=256, A from LLC ring
        const _Float16* hb = hring + (((size_t)((s & 3) * 2 + dir) * S + strip) * 16) * 1024;
        #pragma unroll
        for (int k0 = 0; k0 < 8; ++k0) {
            const _Float16* ha = hb + (size_t)(2 * k0 + (q >> 1)) * 1024 + (wave * 16 + l15) * 16 + (q & 1) * 8;
            f16x8 ah = mk_f16x8(aload_u64(ha), aload_u64(ha + 4));
            int c5 = k0 * 4 + q;
            #pragma unroll
            for (int g = 0; g < 4; ++g)
                acc[g] = mfma16(ah, *(const f16x8*)(recW + wseg(l15, g, c5) * 8), acc[g]);
        }
        // epilogue
        #pragma unroll
        for (int e = 0; e < 4; ++e) {
            int rl = wave * 16 + q * 4 + e;
            float cn = sigm(acc[1][e]) * creg[e] + sigm(acc[0][e]) * tanh_(acc[2][e]);
            creg[e] = cn;
            float h = sigm(acc[3][e]) * tanh_(cn);
            _Float16 h16 = (_Float16)h;
            out0[((size_t)t * Bc + strip * 64 + rl) * 512 + dir * 256 + jblk * 16 + l15] = h16;
            hstage[rl * 16 + l15] = h16;
        }
        __syncthreads();
        {   // cooperative coalesced LLC store of own jblk block (2KB)
            _Float16* wb = hring + ((((size_t)(((s + 1) & 3) * 2 + dir) * S + strip) * 16) + jblk) * 1024;
            astore_u64((u64*)wb + tid, ((const u64*)hstage)[tid]);
        }
        asm volatile("s_waitcnt vmcnt(0)" ::: "memory");
        __syncthreads();
        if (tid == 0)
            astore_i(seq + ((size_t)(((s + 1) & 3) * NI + isl) * 16 + jblk) * 16, s + 1);
    }
}

// ---------------- layer 1 mega kernel: consumers + G1 producers ----------------
// consumers: bid<32S, same shape as l0 but acc-init from G1 ring (no W1/out0 reads).
// producers: bid>=32S, W1 slice (64 gatecols x 512) LDS-resident, G1[t]=out0[t]@W1^T into 8-slot ring.
__global__ __launch_bounds__(256) void l1_mega(
    int S, int sbits, int Bc,
    const _Float16* __restrict__ out0,
    const _Float16* __restrict__ WhhF, const _Float16* __restrict__ WhhB,
    const _Float16* __restrict__ W1F, const _Float16* __restrict__ W1B,
    const float* __restrict__ bF, const float* __restrict__ bB,
    _Float16* __restrict__ hring, float* __restrict__ g1ring,
    int* __restrict__ seq, int* __restrict__ gseq, int* __restrict__ prog)
{
    __shared__ _Float16 smem[32768];   // 64KB, role-dependent
    int tid = threadIdx.x;
    int wave = tid >> 6, lane = tid & 63, l15 = lane & 15, q = lane >> 4;
    int NI = 2 * S;
    int nCons = 32 * S;

    if ((int)blockIdx.x < nCons) {
        // ================= consumer =================
        _Float16* recW = smem;              // 32KB
        _Float16* hstage = smem + 16384;    // 2KB
        int jblk = blockIdx.x & 15;
        int isl = blockIdx.x >> 4;
        int dir = isl >> sbits, strip = isl & (S - 1);
        const _Float16* Whh = dir ? WhhB : WhhF;
        const float* bias = dir ? bB : bF;

        #pragma unroll
        for (int it = 0; it < 8; ++it) {
            int idx = it * 256 + tid;
            int jj = idx >> 7, r = idx & 127;
            int g = r >> 5, c5 = r & 31;
            *(u32x4*)(recW + wseg(jj, g, c5) * 8) =
                *(const u32x4*)(Whh + (size_t)(g * 256 + jblk * 16 + jj) * 256 + c5 * 8);
        }
        __syncthreads();

        float bs[4];
        #pragma unroll
        for (int g = 0; g < 4; ++g) bs[g] = bias[g * 256 + jblk * 16 + l15];

        f32x4 creg = { 0.f, 0.f, 0.f, 0.f };

        #pragma unroll 1
        for (int s = 0; s < 512; ++s) {
            int slot8 = s & 7;
            {   // wait partners' h[s] (lanes 0-15) and the 4 G1 producers (lanes 16-19)
                int* sp = seq + ((size_t)((s & 3) * NI + isl) * 16 + (lane & 15)) * 16;
                int* gp = gseq + ((size_t)(slot8 * NI + isl) * 16 + (((lane - 16) & 3) * 4 + (jblk >> 2))) * 16;
                for (;;) {
                    int ok = 1;
                    if (lane < 16) ok = (aload_i(sp) >= s);
                    else if (lane < 20) ok = (aload_i(gp) >= s + 1);
                    if (__all(ok)) break;
                    __builtin_amdgcn_s_sleep(1);
                }
            }
            asm volatile("" ::: "memory");

            // acc init: bias + G1 fragment (f32, exact)
            f32x4 acc[4];
            const float* gb = g1ring + ((((size_t)(slot8 * 2 + dir) * S + strip) * 4 + wave) * 64) * 64 * 4;
            #pragma unroll
            for (int g = 0; g < 4; ++g) {
                const float* gp4 = gb + ((size_t)(g * 16 + jblk) * 64 + lane) * 4;
                f32x4 gv = mk_f32x4(aload_u64(gp4), aload_u64(gp4 + 2));
                f32x4 bb = { bs[g], bs[g], bs[g], bs[g] };
                acc[g] = gv + bb;
            }
            // recurrent K=256
            const _Float16* hb = hring + (((size_t)((s & 3) * 2 + dir) * S + strip) * 16) * 1024;
            #pragma unroll
            for (int k0 = 0; k0 < 8; ++k0) {
                const _Float16* ha = hb + (size_t)(2 * k0 + (q >> 1)) * 1024 + (wave * 16 + l15) * 16 + (q & 1) * 8;
                f16x8 ah = mk_f16x8(aload_u64(ha), aload_u64(ha + 4));
                int c5 = k0 * 4 + q;
                #pragma unroll
                for (int g = 0; g < 4; ++g)
                    acc[g] = mfma16(ah, *(const f16x8*)(recW + wseg(l15, g, c5) * 8), acc[g]);
            }
            #pragma unroll
            for (int e = 0; e < 4; ++e) {
                int rl = wave * 16 + q * 4 + e;
                float cn = sigm(acc[1][e]) * creg[e] + sigm(acc[0][e]) * tanh_(acc[2][e]);
                creg[e] = cn;
                hstage[rl * 16 + l15] = (_Float16)(sigm(acc[3][e]) * tanh_(cn));
            }
            __syncthreads();
            {
                _Float16* wb = hring + ((((size_t)(((s + 1) & 3) * 2 + dir) * S + strip) * 16) + jblk) * 1024;
                astore_u64((u64*)wb + tid, ((const u64*)hstage)[tid]);
            }
            asm volatile("s_waitcnt vmcnt(0)" ::: "memory");
            __syncthreads();
            if (tid == 0) {
                astore_i(seq + ((size_t)(((s + 1) & 3) * NI + isl) * 16 + jblk) * 16, s + 1);
                astore_i(prog + ((size_t)isl * 16 + jblk) * 16, s + 1);   // monotone progress
            }
        }
    } else {
        // ================= producer =================
        _Float16* Wl = smem;   // 64KB: [64 gatecols][64 chunks swz][8]
        int pb = blockIdx.x - nCons;
        int p = pb & 15;
        int isl = pb >> 4;
        int dir = isl >> sbits, strip = isl & (S - 1);
        const _Float16* W1 = dir ? W1B : W1F;

        #pragma unroll
        for (int it = 0; it < 16; ++it) {
            int idx = it * 256 + tid;          // 4096 x 16B
            int c = idx >> 6, cc = idx & 63;
            int n = 4 * p + (c >> 4);          // ntile
            int grow = (n >> 4) * 256 + (n & 15) * 16 + (c & 15);
            *(u32x4*)(Wl + ((size_t)c * 64 + (cc ^ (c & 7))) * 8) =
                *(const u32x4*)(W1 + (size_t)grow * 512 + cc * 8);
        }
        __syncthreads();

        #pragma unroll 1
        for (int s = 0; s < 512; ++s) {
            if (s >= 8) {   // ring back-pressure: consumers must be past step s-8
                int* pp = prog + ((size_t)isl * 16 + (lane & 15)) * 16;
                for (;;) {
                    int ok = 1;
                    if (lane < 16) ok = (aload_i(pp) >= s - 7);
                    if (__all(ok)) break;
                    __builtin_amdgcn_s_sleep(1);
                }
            }
            int t = dir ? (511 - s) : s;
            f32x4 acc[4];
            f32x4 z = { 0.f, 0.f, 0.f, 0.f };
            acc[0] = z; acc[1] = z; acc[2] = z; acc[3] = z;
            #pragma unroll 4
            for (int k0 = 0; k0 < 16; ++k0) {
                f16x8 aa = *(const f16x8*)(out0 + ((size_t)t * Bc + strip * 64 + wave * 16 + l15) * 512 + k0 * 32 + q * 8);
                int c5 = k0 * 4 + q;
                #pragma unroll
                for (int nt = 0; nt < 4; ++nt) {
                    int col = nt * 16 + l15;
                    f16x8 bb = *(const f16x8*)(Wl + ((size_t)col * 64 + (c5 ^ (col & 7))) * 8);
                    acc[nt] = mfma16(aa, bb, acc[nt]);
                }
            }
            int slot8 = s & 7;
            float* gb = g1ring + ((((size_t)(slot8 * 2 + dir) * S + strip) * 4 + wave) * 64) * 64 * 4;
            #pragma unroll
            for (int nt = 0; nt < 4; ++nt) {
                float* gp4 = gb + ((size_t)(4 * p + nt) * 64 + lane) * 4;
                u64 a0, a1; un_f32x4(acc[nt], &a0, &a1);
                astore_u64(gp4, a0);
                astore_u64(gp4 + 2, a1);
            }
            asm volatile("s_waitcnt vmcnt(0)" ::: "memory");
            __syncthreads();
            if (tid == 0)
                astore_i(gseq + ((size_t)(slot8 * NI + isl) * 16 + p) * 16, s + 1);
        }
    }
}

// ---------------- final FC ----------------
// h1 final = ring slot 0 (h[512]); read via LLC atomics (ring lines are sc0sc1-written).
__global__ __launch_bounds__(64) void fc_kernel(
    int S, const _Float16* __restrict__ hring,
    const float* __restrict__ fcwT, const float* __restrict__ fcb,
    float* __restrict__ out, int b0)
{
    __shared__ float hc[512];
    int b = blockIdx.x, l = threadIdx.x;
    int strip = b >> 6, row = b & 63;
    #pragma unroll
    for (int u = 0; u < 2; ++u) {
        int ui = l * 2 + u;                // 0..127 ull index
        int d = ui >> 6, rem = ui & 63;
        int jb = rem >> 2, part = rem & 3;
        const _Float16* hp = hring + (((size_t)d * S + strip) * 16 + jb) * 1024 + row * 16 + part * 4;
        union { u64 x; _Float16 h[4]; } c; c.x = aload_u64(hp);
        #pragma unroll
        for (int k = 0; k < 4; ++k)
            hc[d * 256 + jb * 16 + part * 4 + k] = (float)c.h[k];
    }
    __syncthreads();
    float acc = fcb[l];
    for (int j = 0; j < 512; ++j) acc += hc[j] * fcwT[j * 64 + l];
    out[(b0 + b) * 64 + l] = acc;
}

// ---------------- host ----------------
extern "C" void kernel_launch(void* const* d_in, const int* in_sizes, int n_in,
                              void* d_out, int out_size, void* d_ws, size_t ws_size,
                              hipStream_t stream)
{
    const float* x     = (const float*)d_in[0];
    const float* wih0f = (const float*)d_in[1];
    const float* whh0f = (const float*)d_in[2];
    const float* b0f   = (const float*)d_in[3];
    const float* wih0b = (const float*)d_in[4];
    const float* whh0b = (const float*)d_in[5];
    const float* b0b   = (const float*)d_in[6];
    const float* wih1f = (const float*)d_in[7];
    const float* whh1f = (const float*)d_in[8];
    const float* b1f   = (const float*)d_in[9];
    const float* wih1b = (const float*)d_in[10];
    const float* whh1b = (const float*)d_in[11];
    const float* b1b   = (const float*)d_in[12];
    const float* fcw   = (const float*)d_in[13];
    const float* fcb   = (const float*)d_in[14];
    float* out = (float*)d_out;
    (void)in_sizes; (void)n_in; (void)out_size;

    // per batch-row bytes: out0 524288 + G1 ring 131072 + h ring 4096
    const size_t per_row = 524288 + 131072 + 4096;
    const size_t fixed   = 24u * 1048576;
    int Bc = 512;
    while (Bc > 64 && fixed + per_row * (size_t)Bc > ws_size) Bc >>= 1;
    const int nb = 512 / Bc;
    const int S = Bc / 64;
    const int sbits = 31 - __builtin_clz((unsigned)S);

    char* pp = (char*)d_ws;
    auto alloc = [&](size_t bytes) -> void* {
        void* r = (void*)pp;
        pp += (bytes + 255) & ~(size_t)255;
        return r;
    };
    _Float16* Whh0f16 = (_Float16*)alloc(262144 * 2);
    _Float16* Whh0b16 = (_Float16*)alloc(262144 * 2);
    _Float16* Whh1f16 = (_Float16*)alloc(262144 * 2);
    _Float16* Whh1b16 = (_Float16*)alloc(262144 * 2);
    _Float16* Wih0pf  = (_Float16*)alloc(32768 * 2);
    _Float16* Wih0pb  = (_Float16*)alloc(32768 * 2);
    _Float16* Wih1f16 = (_Float16*)alloc(524288 * 2);
    _Float16* Wih1b16 = (_Float16*)alloc(524288 * 2);
    _Float16* xpad    = (_Float16*)alloc((size_t)512 * 512 * 32 * 2);
    float*    fcwT    = (float*)alloc(512 * 64 * 4);
    int*      seqA    = (int*)alloc(4 * 16 * 16 * 16 * 4);     // [slot4][isl<=16][jblk][16-int pad]
    int*      gseqA   = (int*)alloc(8 * 16 * 16 * 16 * 4);     // [slot8][isl][p][pad]
    int*      progA   = (int*)alloc(16 * 16 * 16 * 4);         // [isl][jblk][pad]
    _Float16* hring   = (_Float16*)alloc((size_t)4 * 2 * S * 16 * 1024 * 2);
    float*    g1ring  = (float*)alloc((size_t)8 * 2 * S * 4 * 64 * 64 * 4 * 4);
    _Float16* out0    = (_Float16*)alloc((size_t)512 * Bc * 512 * 2);

    cvt_f16<<<1024, 256, 0, stream>>>(whh0f, Whh0f16, 262144);
    cvt_f16<<<1024, 256, 0, stream>>>(whh0b, Whh0b16, 262144);
    cvt_f16<<<1024, 256, 0, stream>>>(whh1f, Whh1f16, 262144);
    cvt_f16<<<1024, 256, 0, stream>>>(whh1b, Whh1b16, 262144);
    cvt_f16<<<2048, 256, 0, stream>>>(wih1f, Wih1f16, 524288);
    cvt_f16<<<2048, 256, 0, stream>>>(wih1b, Wih1b16, 524288);
    pad_wih0_f16<<<128, 256, 0, stream>>>(wih0f, Wih0pf);
    pad_wih0_f16<<<128, 256, 0, stream>>>(wih0b, Wih0pb);
    pad_x_f16<<<32768, 256, 0, stream>>>(x, xpad);
    transpose_fcw<<<128, 256, 0, stream>>>(fcw, fcwT);

    const size_t seqB  = 4 * 16 * 16 * 16 * 4;
    const size_t gseqB = 8 * 16 * 16 * 16 * 4;
    const size_t progB = 16 * 16 * 16 * 4;
    const size_t hringB = (size_t)4 * 2 * S * 16 * 1024 * 2;

    for (int bchunk = 0; bchunk < nb; ++bchunk) {
        int b0 = bchunk * Bc;

        hipMemsetAsync(seqA, 0, seqB, stream);
        hipMemsetAsync(hring, 0, hringB, stream);
        l0_persist<<<32 * S, 256, 0, stream>>>(S, sbits, Bc, b0, xpad,
            Whh0f16, Whh0b16, Wih0pf, Wih0pb, b0f, b0b, hring, seqA, out0);

        hipMemsetAsync(seqA, 0, seqB, stream);
        hipMemsetAsync(gseqA, 0, gseqB, stream);
        hipMemsetAsync(progA, 0, progB, stream);
        hipMemsetAsync(hring, 0, hringB, stream);
        l1_mega<<<64 * S, 256, 0, stream>>>(S, sbits, Bc, out0,
            Whh1f16, Whh1b16, Wih1f16, Wih1b16, b1f, b1b,
            hring, g1ring, seqA, gseqA, progA);

        fc_kernel<<<Bc, 64, 0, stream>>>(S, hring, fcwT, fcb, out, b0);
    }
}

// Round 9
// 7793.873 us; speedup vs baseline: 10.1492x; 1.1825x over previous
//
#include <hip/hip_runtime.h>
#include <stdint.h>

#define DEV static __device__ __forceinline__

typedef float f32x4 __attribute__((ext_vector_type(4)));
typedef unsigned int u32x4 __attribute__((ext_vector_type(4)));
typedef _Float16 f16x8 __attribute__((ext_vector_type(8)));
typedef unsigned long long u64;

DEV float sigm(float x) { return __fdividef(1.0f, 1.0f + __expf(-x)); }
DEV float tanh_(float x) { return 1.0f - __fdividef(2.0f, __expf(2.0f * x) + 1.0f); }

DEV f32x4 mfma16(f16x8 a, f16x8 b, f32x4 c) {
    return __builtin_amdgcn_mfma_f32_16x16x32_f16(a, b, c, 0, 0, 0);
}

// flag ops stay __hip_atomic (R7-validated); poll loops contain no LDS ops so
// flat-op lgkmcnt aliasing cannot serialize anything there.
DEV int aload_i(const int* p) { return __hip_atomic_load(p, __ATOMIC_RELAXED, __HIP_MEMORY_SCOPE_AGENT); }
DEV void astore_i(int* p, int v) { __hip_atomic_store(p, v, __ATOMIC_RELAXED, __HIP_MEMORY_SCOPE_AGENT); }
DEV u64 aload_u64(const void* p) { return __hip_atomic_load((const u64*)p, __ATOMIC_RELAXED, __HIP_MEMORY_SCOPE_AGENT); }

// LLC-coherent (sc0 sc1) vmcnt-only data movement — pipelines, no lgkmcnt alias.
DEV f16x8 gload_h(const _Float16* p) {
    f16x8 v;
    asm volatile("global_load_dwordx4 %0, %1, off sc0 sc1" : "=v"(v) : "v"(p));
    return v;
}
DEV f32x4 gload_g(const float* p) {
    f32x4 v;
    asm volatile("global_load_dwordx4 %0, %1, off sc0 sc1" : "=v"(v) : "v"(p));
    return v;
}
DEV void gstore_u64(void* p, u64 v) {
    asm volatile("global_store_dwordx2 %0, %1, off sc0 sc1" :: "v"(p), "v"(v) : "memory");
}
DEV void gstore_g(void* p, f32x4 v) {
    asm volatile("global_store_dwordx4 %0, %1, off sc0 sc1" :: "v"(p), "v"(v) : "memory");
}
DEV void vmwait8(f16x8& a0, f16x8& a1, f16x8& a2, f16x8& a3,
                 f16x8& a4, f16x8& a5, f16x8& a6, f16x8& a7) {
    asm volatile("s_waitcnt vmcnt(0)"
        : "+v"(a0), "+v"(a1), "+v"(a2), "+v"(a3), "+v"(a4), "+v"(a5), "+v"(a6), "+v"(a7)
        :: "memory");
}
DEV void vmwait12(f16x8& a0, f16x8& a1, f16x8& a2, f16x8& a3,
                  f16x8& a4, f16x8& a5, f16x8& a6, f16x8& a7,
                  f32x4& g0, f32x4& g1, f32x4& g2, f32x4& g3) {
    asm volatile("s_waitcnt vmcnt(0)"
        : "+v"(a0), "+v"(a1), "+v"(a2), "+v"(a3), "+v"(a4), "+v"(a5), "+v"(a6), "+v"(a7),
          "+v"(g0), "+v"(g1), "+v"(g2), "+v"(g3)
        :: "memory");
}

// ---------------- packing pre-passes ----------------
__global__ __launch_bounds__(256) void cvt_f16(const float* __restrict__ src, _Float16* __restrict__ dst, int n) {
    int o = blockIdx.x * 256 + threadIdx.x;
    if (o < n) dst[o] = (_Float16)src[o];
}
__global__ __launch_bounds__(256) void pad_wih0_f16(const float* __restrict__ src, _Float16* __restrict__ dst) {
    int o = blockIdx.x * 256 + threadIdx.x;   // 32768
    int k = o & 31, r = o >> 5;
    dst[o] = (k < 16) ? (_Float16)src[r * 16 + k] : (_Float16)0.f;
}
__global__ __launch_bounds__(256) void pad_x_f16(const float* __restrict__ src, _Float16* __restrict__ dst) {
    int o = blockIdx.x * 256 + threadIdx.x;   // 8388608
    int k = o & 31;
    int t = (o >> 5) & 511;
    int b = o >> 14;
    dst[o] = (k < 16) ? (_Float16)src[((size_t)b * 512 + t) * 16 + k] : (_Float16)0.f;
}
__global__ __launch_bounds__(256) void transpose_fcw(const float* __restrict__ src, float* __restrict__ dst) {
    int o = blockIdx.x * 256 + threadIdx.x;   // 32768
    int j = o >> 6, l = o & 63;
    dst[o] = src[l * 512 + j];
}

// LDS W slice: 16B segment index for (jj in [0,16), gate, c5 = k0*4+q), XOR swizzle
DEV int wseg(int jj, int g, int c5) { return jj * 128 + g * 32 + (c5 ^ (jj & 7)); }

// ---------------- layer 0 persistent (dataflow-sync) ----------------
__global__ __launch_bounds__(256) void l0_persist(
    int S, int sbits, int Bc, int b0,
    const _Float16* __restrict__ xpad,
    const _Float16* __restrict__ WhhF, const _Float16* __restrict__ WhhB,
    const _Float16* __restrict__ WihF, const _Float16* __restrict__ WihB,
    const float* __restrict__ bF, const float* __restrict__ bB,
    _Float16* __restrict__ hring, int* __restrict__ seq, _Float16* __restrict__ out0)
{
    __shared__ _Float16 recW[16384];   // 32KB
    __shared__ _Float16 hstage[1024];  // 2KB
    int tid = threadIdx.x;
    int wave = tid >> 6, lane = tid & 63, l15 = lane & 15, q = lane >> 4;
    int jblk = blockIdx.x & 15;
    int isl = blockIdx.x >> 4;
    int NI = 2 * S;
    int dir = isl >> sbits, strip = isl & (S - 1);

    const _Float16* Whh = dir ? WhhB : WhhF;
    const _Float16* Wih = dir ? WihB : WihF;
    const float* bias = dir ? bB : bF;

    #pragma unroll
    for (int it = 0; it < 8; ++it) {
        int idx = it * 256 + tid;
        int jj = idx >> 7, r = idx & 127;
        int g = r >> 5, c5 = r & 31;
        *(u32x4*)(recW + wseg(jj, g, c5) * 8) =
            *(const u32x4*)(Whh + (size_t)(g * 256 + jblk * 16 + jj) * 256 + c5 * 8);
    }
    __syncthreads();

    float bs[4]; f16x8 bx[4];
    #pragma unroll
    for (int g = 0; g < 4; ++g) {
        bs[g] = bias[g * 256 + jblk * 16 + l15];
        bx[g] = *(const f16x8*)(Wih + (size_t)(g * 256 + jblk * 16 + l15) * 32 + q * 8);
    }

    f32x4 creg = { 0.f, 0.f, 0.f, 0.f };

    #pragma unroll 1
    for (int s = 0; s < 512; ++s) {
        int t = dir ? (511 - s) : s;
        {   // wait for partners' h[s] at slot s&3
            int* sp = seq + ((size_t)((s & 3) * NI + isl) * 16 + (lane & 15)) * 16;
            for (;;) {
                int ok = 1;
                if (lane < 16) ok = (aload_i(sp) >= s);
                if (__all(ok)) break;
                __builtin_amdgcn_s_sleep(1);
            }
        }
        asm volatile("" ::: "memory");

        // issue all 8 h-frag LLC loads up front (pipelined, vmcnt-only)
        const _Float16* hb = hring + (((size_t)((s & 3) * 2 + dir) * S + strip) * 16) * 1024;
        f16x8 ah[8];
        #pragma unroll
        for (int k0 = 0; k0 < 8; ++k0)
            ah[k0] = gload_h(hb + (size_t)(2 * k0 + (q >> 1)) * 1024 + (wave * 16 + l15) * 16 + (q & 1) * 8);

        f32x4 acc[4];
        #pragma unroll
        for (int g = 0; g < 4; ++g) { f32x4 v = { bs[g], bs[g], bs[g], bs[g] }; acc[g] = v; }

        {   // input term K=32 (overlaps h-load latency)
            f16x8 ax = *(const f16x8*)(xpad + ((size_t)(b0 + strip * 64 + wave * 16 + l15) * 512 + t) * 32 + q * 8);
            #pragma unroll
            for (int g = 0; g < 4; ++g) acc[g] = mfma16(ax, bx[g], acc[g]);
        }
        vmwait8(ah[0], ah[1], ah[2], ah[3], ah[4], ah[5], ah[6], ah[7]);
        #pragma unroll
        for (int k0 = 0; k0 < 8; ++k0) {
            int c5 = k0 * 4 + q;
            #pragma unroll
            for (int g = 0; g < 4; ++g)
                acc[g] = mfma16(ah[k0], *(const f16x8*)(recW + wseg(l15, g, c5) * 8), acc[g]);
        }
        // epilogue
        _Float16 h16v[4];
        #pragma unroll
        for (int e = 0; e < 4; ++e) {
            int rl = wave * 16 + q * 4 + e;
            float cn = sigm(acc[1][e]) * creg[e] + sigm(acc[0][e]) * tanh_(acc[2][e]);
            creg[e] = cn;
            float h = sigm(acc[3][e]) * tanh_(cn);
            h16v[e] = (_Float16)h;
            hstage[rl * 16 + l15] = h16v[e];
        }
        __syncthreads();
        {   // cooperative coalesced LLC store of own jblk block (2KB)
            _Float16* wb = hring + ((((size_t)(((s + 1) & 3) * 2 + dir) * S + strip) * 16) + jblk) * 1024;
            gstore_u64((u64*)wb + tid, ((const u64*)hstage)[tid]);
        }
        asm volatile("s_waitcnt vmcnt(0)" ::: "memory");
        __syncthreads();
        if (tid == 0)
            astore_i(seq + ((size_t)(((s + 1) & 3) * NI + isl) * 16 + jblk) * 16, s + 1);
        // out0 (plain cacheable) off the critical path, after the post
        #pragma unroll
        for (int e = 0; e < 4; ++e) {
            int rl = wave * 16 + q * 4 + e;
            out0[((size_t)t * Bc + strip * 64 + rl) * 512 + dir * 256 + jblk * 16 + l15] = h16v[e];
        }
    }
}

// ---------------- layer 1 mega kernel: consumers + G1 producers ----------------
__global__ __launch_bounds__(256) void l1_mega(
    int S, int sbits, int Bc,
    const _Float16* __restrict__ out0,
    const _Float16* __restrict__ WhhF, const _Float16* __restrict__ WhhB,
    const _Float16* __restrict__ W1F, const _Float16* __restrict__ W1B,
    const float* __restrict__ bF, const float* __restrict__ bB,
    _Float16* __restrict__ hring, float* __restrict__ g1ring,
    int* __restrict__ seq, int* __restrict__ gseq, int* __restrict__ prog)
{
    __shared__ _Float16 smem[32768];   // 64KB, role-dependent
    int tid = threadIdx.x;
    int wave = tid >> 6, lane = tid & 63, l15 = lane & 15, q = lane >> 4;
    int NI = 2 * S;
    int nCons = 32 * S;

    if ((int)blockIdx.x < nCons) {
        // ================= consumer =================
        _Float16* recW = smem;
        _Float16* hstage = smem + 16384;
        int jblk = blockIdx.x & 15;
        int isl = blockIdx.x >> 4;
        int dir = isl >> sbits, strip = isl & (S - 1);
        const _Float16* Whh = dir ? WhhB : WhhF;
        const float* bias = dir ? bB : bF;

        #pragma unroll
        for (int it = 0; it < 8; ++it) {
            int idx = it * 256 + tid;
            int jj = idx >> 7, r = idx & 127;
            int g = r >> 5, c5 = r & 31;
            *(u32x4*)(recW + wseg(jj, g, c5) * 8) =
                *(const u32x4*)(Whh + (size_t)(g * 256 + jblk * 16 + jj) * 256 + c5 * 8);
        }
        __syncthreads();

        float bs[4];
        #pragma unroll
        for (int g = 0; g < 4; ++g) bs[g] = bias[g * 256 + jblk * 16 + l15];

        f32x4 creg = { 0.f, 0.f, 0.f, 0.f };

        #pragma unroll 1
        for (int s = 0; s < 512; ++s) {
            int slot8 = s & 7;
            {   // wait partners' h[s] (lanes 0-15) and 4 G1 producers (lanes 16-19)
                int* sp = seq + ((size_t)((s & 3) * NI + isl) * 16 + (lane & 15)) * 16;
                int* gp = gseq + ((size_t)(slot8 * NI + isl) * 16 + (((lane - 16) & 3) * 4 + (jblk >> 2))) * 16;
                for (;;) {
                    int ok = 1;
                    if (lane < 16) ok = (aload_i(sp) >= s);
                    else if (lane < 20) ok = (aload_i(gp) >= s + 1);
                    if (__all(ok)) break;
                    __builtin_amdgcn_s_sleep(1);
                }
            }
            asm volatile("" ::: "memory");

            // issue all LLC loads up front: 8 h frags + 4 G1 frags
            const _Float16* hb = hring + (((size_t)((s & 3) * 2 + dir) * S + strip) * 16) * 1024;
            f16x8 ah[8];
            #pragma unroll
            for (int k0 = 0; k0 < 8; ++k0)
                ah[k0] = gload_h(hb + (size_t)(2 * k0 + (q >> 1)) * 1024 + (wave * 16 + l15) * 16 + (q & 1) * 8);
            const float* gb = g1ring + ((((size_t)(slot8 * 2 + dir) * S + strip) * 4 + wave) * 64) * 64 * 4;
            f32x4 gv[4];
            #pragma unroll
            for (int g = 0; g < 4; ++g)
                gv[g] = gload_g(gb + ((size_t)(g * 16 + jblk) * 64 + lane) * 4);
            vmwait12(ah[0], ah[1], ah[2], ah[3], ah[4], ah[5], ah[6], ah[7],
                     gv[0], gv[1], gv[2], gv[3]);

            f32x4 acc[4];
            #pragma unroll
            for (int g = 0; g < 4; ++g) {
                f32x4 bb = { bs[g], bs[g], bs[g], bs[g] };
                acc[g] = gv[g] + bb;
            }
            #pragma unroll
            for (int k0 = 0; k0 < 8; ++k0) {
                int c5 = k0 * 4 + q;
                #pragma unroll
                for (int g = 0; g < 4; ++g)
                    acc[g] = mfma16(ah[k0], *(const f16x8*)(recW + wseg(l15, g, c5) * 8), acc[g]);
            }
            #pragma unroll
            for (int e = 0; e < 4; ++e) {
                int rl = wave * 16 + q * 4 + e;
                float cn = sigm(acc[1][e]) * creg[e] + sigm(acc[0][e]) * tanh_(acc[2][e]);
                creg[e] = cn;
                hstage[rl * 16 + l15] = (_Float16)(sigm(acc[3][e]) * tanh_(cn));
            }
            __syncthreads();
            {
                _Float16* wb = hring + ((((size_t)(((s + 1) & 3) * 2 + dir) * S + strip) * 16) + jblk) * 1024;
                gstore_u64((u64*)wb + tid, ((const u64*)hstage)[tid]);
            }
            asm volatile("s_waitcnt vmcnt(0)" ::: "memory");
            __syncthreads();
            if (tid == 0) {
                astore_i(seq + ((size_t)(((s + 1) & 3) * NI + isl) * 16 + jblk) * 16, s + 1);
                astore_i(prog + ((size_t)isl * 16 + jblk) * 16, s + 1);
            }
        }
    } else {
        // ================= producer =================
        _Float16* Wl = smem;   // 64KB: [64 gatecols][64 chunks swz][8]
        int pb = blockIdx.x - nCons;
        int p = pb & 15;
        int isl = pb >> 4;
        int dir = isl >> sbits, strip = isl & (S - 1);
        const _Float16* W1 = dir ? W1B : W1F;

        #pragma unroll
        for (int it = 0; it < 16; ++it) {
            int idx = it * 256 + tid;
            int c = idx >> 6, cc = idx & 63;
            int n = 4 * p + (c >> 4);
            int grow = (n >> 4) * 256 + (n & 15) * 16 + (c & 15);
            *(u32x4*)(Wl + ((size_t)c * 64 + (cc ^ (c & 7))) * 8) =
                *(const u32x4*)(W1 + (size_t)grow * 512 + cc * 8);
        }
        __syncthreads();

        #pragma unroll 1
        for (int s = 0; s < 512; ++s) {
            if (s >= 8) {   // ring back-pressure
                int* pp = prog + ((size_t)isl * 16 + (lane & 15)) * 16;
                for (;;) {
                    int ok = 1;
                    if (lane < 16) ok = (aload_i(pp) >= s - 7);
                    if (__all(ok)) break;
                    __builtin_amdgcn_s_sleep(1);
                }
            }
            int t = dir ? (511 - s) : s;
            f32x4 acc[4];
            f32x4 z = { 0.f, 0.f, 0.f, 0.f };
            acc[0] = z; acc[1] = z; acc[2] = z; acc[3] = z;
            #pragma unroll 4
            for (int k0 = 0; k0 < 16; ++k0) {
                f16x8 aa = *(const f16x8*)(out0 + ((size_t)t * Bc + strip * 64 + wave * 16 + l15) * 512 + k0 * 32 + q * 8);
                int c5 = k0 * 4 + q;
                #pragma unroll
                for (int nt = 0; nt < 4; ++nt) {
                    int col = nt * 16 + l15;
                    f16x8 bb = *(const f16x8*)(Wl + ((size_t)col * 64 + (c5 ^ (col & 7))) * 8);
                    acc[nt] = mfma16(aa, bb, acc[nt]);
                }
            }
            int slot8 = s & 7;
            float* gb = g1ring + ((((size_t)(slot8 * 2 + dir) * S + strip) * 4 + wave) * 64) * 64 * 4;
            #pragma unroll
            for (int nt = 0; nt < 4; ++nt)
                gstore_g(gb + ((size_t)(4 * p + nt) * 64 + lane) * 4, acc[nt]);
            asm volatile("s_waitcnt vmcnt(0)" ::: "memory");
            __syncthreads();
            if (tid == 0)
                astore_i(gseq + ((size_t)(slot8 * NI + isl) * 16 + p) * 16, s + 1);
        }
    }
}

// ---------------- final FC ----------------
__global__ __launch_bounds__(64) void fc_kernel(
    int S, const _Float16* __restrict__ hring,
    const float* __restrict__ fcwT, const float* __restrict__ fcb,
    float* __restrict__ out, int b0)
{
    __shared__ float hc[512];
    int b = blockIdx.x, l = threadIdx.x;
    int strip = b >> 6, row = b & 63;
    #pragma unroll
    for (int u = 0; u < 2; ++u) {
        int ui = l * 2 + u;
        int d = ui >> 6, rem = ui & 63;
        int jb = rem >> 2, part = rem & 3;
        const _Float16* hp = hring + (((size_t)d * S + strip) * 16 + jb) * 1024 + row * 16 + part * 4;
        union { u64 x; _Float16 h[4]; } c; c.x = aload_u64(hp);
        #pragma unroll
        for (int k = 0; k < 4; ++k)
            hc[d * 256 + jb * 16 + part * 4 + k] = (float)c.h[k];
    }
    __syncthreads();
    float acc = fcb[l];
    for (int j = 0; j < 512; ++j) acc += hc[j] * fcwT[j * 64 + l];
    out[(b0 + b) * 64 + l] = acc;
}

// ---------------- host ----------------
extern "C" void kernel_launch(void* const* d_in, const int* in_sizes, int n_in,
                              void* d_out, int out_size, void* d_ws, size_t ws_size,
                              hipStream_t stream)
{
    const float* x     = (const float*)d_in[0];
    const float* wih0f = (const float*)d_in[1];
    const float* whh0f = (const float*)d_in[2];
    const float* b0f   = (const float*)d_in[3];
    const float* wih0b = (const float*)d_in[4];
    const float* whh0b = (const float*)d_in[5];
    const float* b0b   = (const float*)d_in[6];
    const float* wih1f = (const float*)d_in[7];
    const float* whh1f = (const float*)d_in[8];
    const float* b1f   = (const float*)d_in[9];
    const float* wih1b = (const float*)d_in[10];
    const float* whh1b = (const float*)d_in[11];
    const float* b1b   = (const float*)d_in[12];
    const float* fcw   = (const float*)d_in[13];
    const float* fcb   = (const float*)d_in[14];
    float* out = (float*)d_out;
    (void)in_sizes; (void)n_in; (void)out_size;

    const size_t per_row = 524288 + 131072 + 4096;
    const size_t fixed   = 24u * 1048576;
    int Bc = 512;
    while (Bc > 64 && fixed + per_row * (size_t)Bc > ws_size) Bc >>= 1;
    const int nb = 512 / Bc;
    const int S = Bc / 64;
    const int sbits = 31 - __builtin_clz((unsigned)S);

    char* pp = (char*)d_ws;
    auto alloc = [&](size_t bytes) -> void* {
        void* r = (void*)pp;
        pp += (bytes + 255) & ~(size_t)255;
        return r;
    };
    _Float16* Whh0f16 = (_Float16*)alloc(262144 * 2);
    _Float16* Whh0b16 = (_Float16*)alloc(262144 * 2);
    _Float16* Whh1f16 = (_Float16*)alloc(262144 * 2);
    _Float16* Whh1b16 = (_Float16*)alloc(262144 * 2);
    _Float16* Wih0pf  = (_Float16*)alloc(32768 * 2);
    _Float16* Wih0pb  = (_Float16*)alloc(32768 * 2);
    _Float16* Wih1f16 = (_Float16*)alloc(524288 * 2);
    _Float16* Wih1b16 = (_Float16*)alloc(524288 * 2);
    _Float16* xpad    = (_Float16*)alloc((size_t)512 * 512 * 32 * 2);
    float*    fcwT    = (float*)alloc(512 * 64 * 4);
    int*      seqA    = (int*)alloc(4 * 16 * 16 * 16 * 4);
    int*      gseqA   = (int*)alloc(8 * 16 * 16 * 16 * 4);
    int*      progA   = (int*)alloc(16 * 16 * 16 * 4);
    _Float16* hring   = (_Float16*)alloc((size_t)4 * 2 * S * 16 * 1024 * 2);
    float*    g1ring  = (float*)alloc((size_t)8 * 2 * S * 4 * 64 * 64 * 4 * 4);
    _Float16* out0    = (_Float16*)alloc((size_t)512 * Bc * 512 * 2);

    cvt_f16<<<1024, 256, 0, stream>>>(whh0f, Whh0f16, 262144);
    cvt_f16<<<1024, 256, 0, stream>>>(whh0b, Whh0b16, 262144);
    cvt_f16<<<1024, 256, 0, stream>>>(whh1f, Whh1f16, 262144);
    cvt_f16<<<1024, 256, 0, stream>>>(whh1b, Whh1b16, 262144);
    cvt_f16<<<2048, 256, 0, stream>>>(wih1f, Wih1f16, 524288);
    cvt_f16<<<2048, 256, 0, stream>>>(wih1b, Wih1b16, 524288);
    pad_wih0_f16<<<128, 256, 0, stream>>>(wih0f, Wih0pf);
    pad_wih0_f16<<<128, 256, 0, stream>>>(wih0b, Wih0pb);
    pad_x_f16<<<32768, 256, 0, stream>>>(x, xpad);
    transpose_fcw<<<128, 256, 0, stream>>>(fcw, fcwT);

    const size_t seqB  = 4 * 16 * 16 * 16 * 4;
    const size_t gseqB = 8 * 16 * 16 * 16 * 4;
    const size_t progB = 16 * 16 * 16 * 4;
    const size_t hringB = (size_t)4 * 2 * S * 16 * 1024 * 2;

    for (int bchunk = 0; bchunk < nb; ++bchunk) {
        int b0 = bchunk * Bc;

        hipMemsetAsync(seqA, 0, seqB, stream);
        hipMemsetAsync(hring, 0, hringB, stream);
        l0_persist<<<32 * S, 256, 0, stream>>>(S, sbits, Bc, b0, xpad,
            Whh0f16, Whh0b16, Wih0pf, Wih0pb, b0f, b0b, hring, seqA, out0);

        hipMemsetAsync(seqA, 0, seqB, stream);
        hipMemsetAsync(gseqA, 0, gseqB, stream);
        hipMemsetAsync(progA, 0, progB, stream);
        hipMemsetAsync(hring, 0, hringB, stream);
        l1_mega<<<64 * S, 256, 0, stream>>>(S, sbits, Bc, out0,
            Whh1f16, Whh1b16, Wih1f16, Wih1b16, b1f, b1b,
            hring, g1ring, seqA, gseqA, progA);

        fc_kernel<<<Bc, 64, 0, stream>>>(S, hring, fcwT, fcb, out, b0);
    }
}